// Round 7
// baseline (230.637 us; speedup 1.0000x reference)
//
#include <hip/hip_runtime.h>
#include <hip/hip_bf16.h>
#include <math.h>

// Problem constants
#define T_ 4
#define N_ 16
#define F_ 6
#define L_ 1024
#define A_ 21
#define K_ 20
#define U_ 256
#define LOUT 1005            // L - K + 1
#define NIMG 384             // T*N*F
#define SZ_S (T_*N_*U_)      // 16384
#define SZ_R (K_*A_*U_)      // 107520

// Packed-X geometry: row stride 24 shorts (48 B). For output row l, contraction
// slot c maps to tap=c/24, col=c%24 (independent of l) -> contiguous aligned
// K-window. Max valid slot = 19*24+20 = 476 -> 30 K-steps of 16 (480).
#define XPR 24               // shorts per packed row
#define XROWS 1056           // padded rows per image
#define NST 30               // K-steps of 16 slots
#define RT_SHORTS (NST * U_ * 16)   // 122880 shorts = 240 KB

typedef __attribute__((ext_vector_type(8))) short short8;    // 8 bf16
typedef __attribute__((ext_vector_type(4))) float f32x4;
typedef __attribute__((ext_vector_type(16))) float f32x16;   // 32x32 acc

__device__ __forceinline__ unsigned short f2bf(float f) {
  unsigned int u = __float_as_uint(f);
  u += 0x7FFFu + ((u >> 16) & 1u);   // round to nearest even
  return (unsigned short)(u >> 16);
}

__device__ __forceinline__ void atomicMaxF(float* addr, float val) {
  if (val >= 0.f) atomicMax((int*)addr, __float_as_int(val));
  else            atomicMin((unsigned int*)addr, __float_as_uint(val));
}

// Async global->LDS, 16B per lane. LDS dest is wave-uniform base + lane*16.
__device__ __forceinline__ void gload_lds16(const void* g, void* l) {
  __builtin_amdgcn_global_load_lds(
      (const __attribute__((address_space(1))) void*)g,
      (__attribute__((address_space(3))) void*)l, 16, 0, 0);
}

// S init to -inf, R (fp32, exact) into d_out, and Rt = bf16 R scattered into
// 16-slot step order: Rt[(s>>4)*(U*16) + u*16 + (s&15)], s = k*24 + a.
// Pad slots zeroed beforehand by hipMemsetAsync.
__global__ void prep_kernel(const float* __restrict__ P_logit,
                            const float* __restrict__ Q,
                            float* __restrict__ out,
                            unsigned short* __restrict__ Rt) {
  int tid = blockIdx.x * blockDim.x + threadIdx.x;
  if (tid < SZ_S) out[tid] = -INFINITY;
  if (tid >= K_ * U_) return;
  int k = tid / U_;
  int u = tid - k * U_;
  const float* pl = P_logit + (size_t)k * A_ * U_ + u;
  float v[A_];
  float m = -INFINITY;
#pragma unroll
  for (int a = 0; a < A_; ++a) { v[a] = pl[(size_t)a * U_]; m = fmaxf(m, v[a]); }
  float s = 0.f;
#pragma unroll
  for (int a = 0; a < A_; ++a) { v[a] = expf(v[a] - m); s += v[a]; }
  float qs = 0.f;
#pragma unroll
  for (int a = 0; a < A_; ++a) qs += Q[a];
  float eps = qs * (1.0f / A_);
  float invs = 1.f / s;
  float* Rout = out + SZ_S;
#pragma unroll
  for (int a = 0; a < A_; ++a) {
    float r = logf(fmaxf(v[a] * invs / Q[a], eps));
    Rout[(size_t)(k * A_ + a) * U_ + u] = r;
    int sl = k * XPR + a;
    Rt[(size_t)(sl >> 4) * (U_ * 16) + u * 16 + (sl & 15)] = f2bf(r);
  }
}

// X (fp32 [n][1024][21]) -> Xp (bf16 [n][1056][24], zero-padded both dims).
__global__ void xconv_kernel(const float* __restrict__ X,
                             unsigned int* __restrict__ Xp32) {
  int t = blockIdx.x * blockDim.x + threadIdx.x;
  if (t >= NIMG * XROWS * 12) return;
  int w  = t % 12;
  int rl = t / 12;                 // n*XROWS + row
  int row = rl % XROWS;
  int n   = rl / XROWS;
  int c0 = w * 2;
  float v0 = 0.f, v1 = 0.f;
  if (row < L_) {
    const float* xr = X + ((size_t)n * L_ + row) * A_;
    if (c0 < A_)     v0 = xr[c0];
    if (c0 + 1 < A_) v1 = xr[c0 + 1];
  }
  unsigned int o = (unsigned int)f2bf(v0) | ((unsigned int)f2bf(v1) << 16);
  Xp32[(size_t)rl * 12 + w] = o;
}

// Conv as one GEMM with 32x32x16 MFMA: M=u (A=R), N=l (B=packed-X), K=480.
// A/B frag: row/col = lane&31, k = (lane>>5)*8 + j.
// C/D frag: col = lane&31, row = (reg&3) + 8*(reg>>2) + 4*(lane>>5)  [m74/m101].
// X window (8 KB) staged once via global_load_lds; one barrier total.
// Both operands double-buffered: X one step ahead (ds latency), R two ahead
// (L2 latency). Block 128l x 128u, 4 waves (2x2), wave 64u x 64l (2x2 frags).
__global__ __launch_bounds__(256, 4) void conv_kernel(
    const unsigned short* __restrict__ Xp,
    const unsigned short* __restrict__ Rt,
    float* __restrict__ out) {
  __shared__ __align__(16) unsigned short lds_x[4096];   // 8 KB

  const int n  = blockIdx.z;
  const int l0 = blockIdx.y * 128;
  const int u0 = blockIdx.x * 128;
  const int wid  = threadIdx.x >> 6;
  const int lane = threadIdx.x & 63;

  // Stage packed X rows [l0 ..] : 8 x 1KB chunks (2 per wave).
  const char* xsrc = (const char*)Xp + ((size_t)n * XROWS + l0) * (XPR * 2);
#pragma unroll
  for (int r = 0; r < 2; ++r) {
    int c = wid * 2 + r;
    gload_lds16(xsrc + c * 1024 + lane * 16, (char*)lds_x + c * 1024);
  }
  asm volatile("s_waitcnt vmcnt(0)" ::: "memory");
  __syncthreads();

  const int wl = wid >> 1;
  const int wu = wid & 1;
  const int fl = lane & 31;            // frag row (A: u) / col (B: l)
  const int hi = lane >> 5;            // k sub-chunk (8 shorts)

  f32x16 zero;
#pragma unroll
  for (int i = 0; i < 16; ++i) zero[i] = 0.f;
  f32x16 a00 = zero, a01 = zero, a10 = zero, a11 = zero;  // acc[ut][lt]

  // R frag(t, ut) = rb + t*4096 + ut*512 (shorts); each wave instr = 1 KB L2
  const unsigned short* rb = Rt + (size_t)(u0 + wu * 64 + fl) * 16 + hi * 8;
  // X frag(t, lt) = xb + lt*768 + t*16 (shorts, LDS)
  const unsigned short* xb = lds_x + (wl * 64 + fl) * XPR + hi * 8;

  short8 xA0 = *(const short8*)(xb);
  short8 xA1 = *(const short8*)(xb + 32 * XPR);
  short8 rA0 = *(const short8*)(rb);
  short8 rA1 = *(const short8*)(rb + 512);
  short8 rB0 = *(const short8*)(rb + 4096);
  short8 rB1 = *(const short8*)(rb + 4096 + 512);

#pragma unroll 1
  for (int s = 0; s < NST; s += 2) {
    const int s2 = (s + 2 < NST) ? s + 2 : NST - 1;   // branchless clamp
    const int s3 = (s + 3 < NST) ? s + 3 : NST - 1;
    short8 xB0 = *(const short8*)(xb + (s + 1) * 16);
    short8 xB1 = *(const short8*)(xb + 32 * XPR + (s + 1) * 16);
    short8 rn0 = *(const short8*)(rb + (size_t)s2 * 4096);
    short8 rn1 = *(const short8*)(rb + (size_t)s2 * 4096 + 512);
    a00 = __builtin_amdgcn_mfma_f32_32x32x16_bf16(rA0, xA0, a00, 0, 0, 0);
    a01 = __builtin_amdgcn_mfma_f32_32x32x16_bf16(rA0, xA1, a01, 0, 0, 0);
    a10 = __builtin_amdgcn_mfma_f32_32x32x16_bf16(rA1, xA0, a10, 0, 0, 0);
    a11 = __builtin_amdgcn_mfma_f32_32x32x16_bf16(rA1, xA1, a11, 0, 0, 0);
    short8 xN0 = *(const short8*)(xb + s2 * 16);
    short8 xN1 = *(const short8*)(xb + 32 * XPR + s2 * 16);
    short8 rm0 = *(const short8*)(rb + (size_t)s3 * 4096);
    short8 rm1 = *(const short8*)(rb + (size_t)s3 * 4096 + 512);
    a00 = __builtin_amdgcn_mfma_f32_32x32x16_bf16(rB0, xB0, a00, 0, 0, 0);
    a01 = __builtin_amdgcn_mfma_f32_32x32x16_bf16(rB0, xB1, a01, 0, 0, 0);
    a10 = __builtin_amdgcn_mfma_f32_32x32x16_bf16(rB1, xB0, a10, 0, 0, 0);
    a11 = __builtin_amdgcn_mfma_f32_32x32x16_bf16(rB1, xB1, a11, 0, 0, 0);
    rA0 = rn0; rA1 = rn1; rB0 = rm0; rB1 = rm1; xA0 = xN0; xA1 = xN1;
  }

  // Epilogue. Lane holds, per frag: col l = ...+fl (fixed), rows
  // u = ut*32 + 8*rq + 4*hi + (0..3) per f32x4 quad -> 16B contiguous stores.
  float* Z = out + SZ_S + SZ_R;
  f32x4 pm[2][4];                      // [ut][rq], compile-time indexed only
#pragma unroll
  for (int ut = 0; ut < 2; ++ut)
#pragma unroll
    for (int rq = 0; rq < 4; ++rq)
#pragma unroll
      for (int j = 0; j < 4; ++j) pm[ut][rq][j] = -INFINITY;

#define EPILOG(ACC, UT, LT)                                                 \
  {                                                                         \
    const int l = l0 + wl * 64 + (LT) * 32 + fl;                            \
    if (l < LOUT) {                                                         \
      float* zrow = Z + ((size_t)n * LOUT + l) * U_ + u0 + wu * 64 +        \
                    (UT) * 32 + hi * 4;                                     \
      _Pragma("unroll")                                                     \
      for (int rq = 0; rq < 4; ++rq) {                                      \
        f32x4 v;                                                            \
        _Pragma("unroll")                                                   \
        for (int j = 0; j < 4; ++j) v[j] = ACC[4 * rq + j];                 \
        *(f32x4*)(zrow + 8 * rq) = v;                                       \
        _Pragma("unroll")                                                   \
        for (int j = 0; j < 4; ++j)                                         \
          pm[UT][rq][j] = fmaxf(pm[UT][rq][j], v[j]);                       \
      }                                                                     \
    }                                                                       \
  }

  EPILOG(a00, 0, 0)
  EPILOG(a01, 0, 1)
  EPILOG(a10, 1, 0)
  EPILOG(a11, 1, 1)
#undef EPILOG

  // Max over the frag's 32 cols (l): xor-reduce within lane&31 (hi preserved).
#pragma unroll
  for (int off = 1; off < 32; off <<= 1)
#pragma unroll
    for (int ut = 0; ut < 2; ++ut)
#pragma unroll
      for (int rq = 0; rq < 4; ++rq)
#pragma unroll
        for (int j = 0; j < 4; ++j)
          pm[ut][rq][j] = fmaxf(pm[ut][rq][j], __shfl_xor(pm[ut][rq][j], off));

  if (fl == 0) {                       // lanes 0 and 32 (hi = 0/1)
    const int tn = n / F_;
    float* Sp = out + (size_t)tn * U_ + u0 + wu * 64 + hi * 4;
#pragma unroll
    for (int ut = 0; ut < 2; ++ut)
#pragma unroll
      for (int rq = 0; rq < 4; ++rq)
#pragma unroll
        for (int j = 0; j < 4; ++j)
          atomicMaxF(Sp + ut * 32 + 8 * rq + j, pm[ut][rq][j]);
  }
}

extern "C" void kernel_launch(void* const* d_in, const int* in_sizes, int n_in,
                              void* d_out, int out_size, void* d_ws, size_t ws_size,
                              hipStream_t stream) {
  const float* X       = (const float*)d_in[0];
  const float* P_logit = (const float*)d_in[1];
  const float* Q       = (const float*)d_in[2];
  float* out = (float*)d_out;

  unsigned short* Rt = (unsigned short*)d_ws;            // 240 KB (pad to 256)
  const size_t rt_bytes = (size_t)RT_SHORTS * 2;
  unsigned short* Xp = (unsigned short*)((char*)d_ws + 262144);
  // Xp: NIMG*XROWS*24 shorts (~18.6 MB) + 8 KB slack for last-block LDS
  // stage over-read (staged-but-never-consumed rows).

  hipMemsetAsync(Rt, 0, rt_bytes, stream);   // zero pad slots of Rt
  hipLaunchKernelGGL(prep_kernel, dim3(64), dim3(256), 0, stream,
                     P_logit, Q, out, Rt);
  int xthreads = NIMG * XROWS * 12;
  hipLaunchKernelGGL(xconv_kernel, dim3((xthreads + 255) / 256), dim3(256),
                     0, stream, X, (unsigned int*)Xp);
  dim3 grid(2, 8, NIMG);   // u-tiles, l-tiles, images
  hipLaunchKernelGGL(conv_kernel, grid, dim3(256), 0, stream, Xp, Rt, out);
}